// Round 1
// baseline (39.901 us; speedup 1.0000x reference)
//
#include <hip/hip_runtime.h>

#define BATCH   1024
#define IN_DIM  512
#define OUT_DIM 256
#define RB      2   // batch rows per block

// Fully fused tropical block:
//   h1 = min_plus(x, W1); out  = max_i(h1+W2) + b2
//   hm = min_plus(x, Wm); sc   = max_i(hm+Ws) + bs
//   result = min(out, sc)
// One thread per output column j (coalesced weight loads, 256B/wave),
// RB=2 batch rows per block -> grid 512 blocks = 2 blocks/CU = 2 waves/SIMD.
// Stage-1 result staged in 4KB LDS, read back as wave-uniform broadcasts.
__global__ __launch_bounds__(256, 2) void tropical_fused(
    const float* __restrict__ x,
    const float* __restrict__ W1,
    const float* __restrict__ W2,
    const float* __restrict__ b2,
    const float* __restrict__ Wm,
    const float* __restrict__ Ws,
    const float* __restrict__ bs,
    float* __restrict__ out)
{
    const int j    = threadIdx.x;        // output column 0..255
    const int row0 = blockIdx.x * RB;    // first batch row of this block

    __shared__ float hs1[RB][OUT_DIM];   // min_plus(x, W1) rows
    __shared__ float hsm[RB][OUT_DIM];   // min_plus(x, Wm) rows

    const float INF = __builtin_huge_valf();

    // ---------- stage 1: min-plus over K = IN_DIM, both weight mats ----------
    float a10 = INF, a11 = INF, am0 = INF, am1 = INF;

    const float* xr0 = x + (size_t)row0 * IN_DIM;   // block-uniform address
    const float* xr1 = xr0 + IN_DIM;                // -> s_load candidates

    #pragma unroll 8
    for (int k = 0; k < IN_DIM; ++k) {
        const float w1 = W1[k * OUT_DIM + j];
        const float wm = Wm[k * OUT_DIM + j];
        const float x0 = xr0[k];
        const float x1 = xr1[k];
        a10 = fminf(a10, x0 + w1);
        a11 = fminf(a11, x1 + w1);
        am0 = fminf(am0, x0 + wm);
        am1 = fminf(am1, x1 + wm);
    }

    hs1[0][j] = a10;
    hs1[1][j] = a11;
    hsm[0][j] = am0;
    hsm[1][j] = am1;
    __syncthreads();

    // ---------- stage 2: max-plus over K = OUT_DIM, both paths ----------
    float c10 = -INF, c11 = -INF, cm0 = -INF, cm1 = -INF;

    #pragma unroll 4
    for (int i = 0; i < OUT_DIM; ++i) {
        const float w2 = W2[i * OUT_DIM + j];
        const float ws = Ws[i * OUT_DIM + j];
        const float h10 = hs1[0][i];     // wave-uniform LDS broadcast
        const float h11 = hs1[1][i];
        const float hm0 = hsm[0][i];
        const float hm1 = hsm[1][i];
        c10 = fmaxf(c10, h10 + w2);
        c11 = fmaxf(c11, h11 + w2);
        cm0 = fmaxf(cm0, hm0 + ws);
        cm1 = fmaxf(cm1, hm1 + ws);
    }

    // ---------- epilogue: bias + residual min ----------
    const float bb2 = b2[j];
    const float bbs = bs[j];
    const float o0 = fminf(c10 + bb2, cm0 + bbs);
    const float o1 = fminf(c11 + bb2, cm1 + bbs);

    out[(size_t)row0 * OUT_DIM + j]       = o0;
    out[((size_t)row0 + 1) * OUT_DIM + j] = o1;
}

extern "C" void kernel_launch(void* const* d_in, const int* in_sizes, int n_in,
                              void* d_out, int out_size, void* d_ws, size_t ws_size,
                              hipStream_t stream) {
    const float* x  = (const float*)d_in[0];
    const float* W1 = (const float*)d_in[1];
    const float* W2 = (const float*)d_in[2];
    const float* b2 = (const float*)d_in[3];
    const float* Wm = (const float*)d_in[4];
    const float* Ws = (const float*)d_in[5];
    const float* bs = (const float*)d_in[6];
    float* out = (float*)d_out;

    dim3 grid(BATCH / RB);   // 512 blocks
    dim3 block(OUT_DIM);     // 256 threads, one per output column
    tropical_fused<<<grid, block, 0, stream>>>(x, W1, W2, b2, Wm, Ws, bs, out);
}